// Round 17
// baseline (120.013 us; speedup 1.0000x reference)
//
#include <hip/hip_runtime.h>

// x: (128, 55, 55, 96) NHWC fp32; kernel: (96, 5, 5) fp32 depthwise; out = x + dwconv(x,k)
#define NB 128
#define HW 55
#define IMG (HW * HW)            // 3025
#define CH 96
#define GROUPS 24                // float4 channel-groups
#define TAPS 25
#define NPIX (NB * IMG)          // 387,200
#define RSTRIP 5                 // rows per conv block (55 = 5*11)
#define NSTRIP (HW / RSTRIP)     // 11
#define NWG1 (NB * NSTRIP)       // 1408 conv blocks
#define TOTALF4 (NPIX * GROUPS)  // 9,292,800
#define GCHUNK 4                 // compact-buffer group capacity
#define SLOTG 32                 // per-group slot capacity
#define NXCD 8
#define SROWS (RSTRIP + 4)       // 9 staged rows (halo +-2)
#define SPIX (RSTRIP * HW)       // 275 strip pixels
#define STAGEN (SROWS * HW)      // 495 staged pixels
#define STREAM_BLOCKS 2048       // G11: capped grid + grid-stride

typedef float v4f __attribute__((ext_vector_type(4)));

// ---- workspace ----
// float4 wslot[24][SLOTG]; int2 dslot[24][SLOTG] ({dh+2, dw}); int tapflag[24];
// int gact[24]; int nga, nspad, amask; pad; v4f cvbuf[NPIX][<=GCHUNK]

__global__ void repack_kernel(const float* __restrict__ k,
                              float4* __restrict__ wslot,
                              int2* __restrict__ dslot,
                              int* __restrict__ tapflag,
                              int* __restrict__ gact,
                              int* __restrict__ nga,
                              int* __restrict__ nspad,
                              int* __restrict__ amask) {
    __shared__ int s_ns[GROUPS];
    int g = threadIdx.x;
    if (g < GROUPS) {
        int ns = 0;
        for (int tap = 0; tap < TAPS; ++tap) {
            float w0 = k[(4 * g + 0) * TAPS + tap];
            float w1 = k[(4 * g + 1) * TAPS + tap];
            float w2 = k[(4 * g + 2) * TAPS + tap];
            float w3 = k[(4 * g + 3) * TAPS + tap];
            if (w0 != 0.f || w1 != 0.f || w2 != 0.f || w3 != 0.f) {
                int dh = tap / 5 - 2, dw = tap % 5 - 2;
                wslot[g * SLOTG + ns] = make_float4(w0, w1, w2, w3);
                dslot[g * SLOTG + ns] = make_int2(dh + 2, dw);
                ++ns;
            }
        }
        for (int s = ns; s < SLOTG; ++s) {           // pads: weight 0 -> contribute 0
            wslot[g * SLOTG + s] = make_float4(0.f, 0.f, 0.f, 0.f);
            dslot[g * SLOTG + s] = make_int2(2, 0);  // center, always valid
        }
        tapflag[g] = (ns > 0) ? 1 : 0;
        s_ns[g] = ns;
    }
    __syncthreads();
    if (threadIdx.x == 0) {
        int na = 0, m = 0, msk = 0;
        for (int gg = 0; gg < GROUPS; ++gg)
            if (s_ns[gg] > 0) {
                gact[na++] = gg;
                msk |= (1 << gg);
                m = m > s_ns[gg] ? m : s_ns[gg];
            }
        *nga = na;
        *nspad = (m + 7) & ~7;
        *amask = msk;
    }
}

// ---- K1: conv deltas for first min(nga,GCHUNK) active groups -> compact cvbuf ----
// Plain stores: cvbuf stays L2/L3-warm for the stream kernel.
__global__ __launch_bounds__(256) void conv_kernel(const float* __restrict__ x,
                                                   const float4* __restrict__ wslot,
                                                   const int2* __restrict__ dslot,
                                                   const int* __restrict__ gact,
                                                   const int* __restrict__ p_nga,
                                                   const int* __restrict__ p_nspad,
                                                   v4f* __restrict__ cvbuf) {
    __shared__ v4f s_x[GCHUNK * STAGEN];      // planar halo tile 31680 B
    __shared__ float4 s_w[GCHUNK * 8];
    __shared__ int s_d[GCHUNK * 8];           // packed (dh+2)<<8|(dw+2)

    int cn = *p_nga;
    if (cn > GCHUNK) cn = GCHUNK;
    if (cn == 0) return;
    const int nsb = (*p_nspad) >> 3;

    const int q = NWG1 / NXCD, r = NWG1 % NXCD;
    int xcd = blockIdx.x & (NXCD - 1);
    int bidx = blockIdx.x >> 3;
    int swz = (xcd < r ? xcd * (q + 1) : r * (q + 1) + (xcd - r) * q) + bidx;

    const int n = swz / NSTRIP;
    const int strip = swz % NSTRIP;
    const int h0 = strip * RSTRIP;
    const int tid = threadIdx.x;
    const int pixbase = n * IMG + h0 * HW;
    const v4f* x4 = (const v4f*)x;

    if (tid < cn * 8) {                       // stage first slot batch
        int ci = tid >> 3, s = tid & 7;
        int gg = gact[ci];
        s_w[tid] = wslot[gg * SLOTG + s];
        int2 dd = dslot[gg * SLOTG + s];
        s_d[tid] = (dd.x << 8) | (dd.y + 2);
    }
    // stage x halo tile (coalesced; out-of-image rows -> zeros); planar layout
    const int stcnt = STAGEN * cn;
    const int wcn = HW * cn;
    for (int i = tid; i < stcnt; i += 256) {
        int srow = i / wcn;
        int rem2 = i - srow * wcn;
        int pix = rem2 / cn;
        int ci = rem2 - pix * cn;
        int h = h0 - 2 + srow;
        v4f v = {0.f, 0.f, 0.f, 0.f};
        if ((unsigned)h < (unsigned)HW)
            v = x4[(n * IMG + h * HW + pix) * GROUPS + gact[ci]];
        s_x[ci * STAGEN + srow * HW + pix] = v;
    }
    __syncthreads();

    // lane-dense conv; lane order ci-fastest -> fully dense 16B/lane stores
    const int acnt = SPIX * cn;
    for (int j = tid; j < acnt; j += 256) {
        int pa = j / cn;
        int ci = j - pa * cn;
        int rr = pa / HW;
        int pix = pa - rr * HW;
        const v4f* sxg = s_x + ci * STAGEN;
        v4f acc = {0.f, 0.f, 0.f, 0.f};
#pragma unroll
        for (int si = 0; si < 8; ++si) {
            int d = s_d[ci * 8 + si];
            int srow = rr + (d >> 8);
            int pix2 = pix + (d & 255) - 2;
            bool valid = (unsigned)pix2 < (unsigned)HW;
            float sc = valid ? 1.f : 0.f;
            int p2 = valid ? pix2 : 0;
            v4f xv = sxg[srow * HW + p2];
            float4 wv = s_w[ci * 8 + si];
            acc.x += (wv.x * sc) * xv.x;
            acc.y += (wv.y * sc) * xv.y;
            acc.z += (wv.z * sc) * xv.z;
            acc.w += (wv.w * sc) * xv.w;
        }
        for (int sb = 1; sb < nsb; ++sb) {    // rare tail (generality; none here)
            int gg = gact[ci];
#pragma unroll
            for (int si = 0; si < 8; ++si) {
                int s = sb * 8 + si;
                int2 dd = dslot[gg * SLOTG + s];
                int srow = rr + dd.x;
                int pix2 = pix + dd.y;
                bool valid = (unsigned)pix2 < (unsigned)HW;
                float sc = valid ? 1.f : 0.f;
                int p2 = valid ? pix2 : 0;
                v4f xv = sxg[srow * HW + p2];
                float4 wv = wslot[gg * SLOTG + s];
                acc.x += (wv.x * sc) * xv.x;
                acc.y += (wv.y * sc) * xv.y;
                acc.z += (wv.z * sc) * xv.z;
                acc.w += (wv.w * sc) * xv.w;
            }
        }
        cvbuf[(size_t)(pixbase + pa) * cn + ci] = acc;   // plain store (L2-warm)
    }
}

// ---- K2: m13-pattern stream: 2048 blocks, grid-stride, plain stores ----
__global__ __launch_bounds__(256) void stream_kernel(const float* __restrict__ x,
                                                     const v4f* __restrict__ cvbuf,
                                                     const float4* __restrict__ wslot,
                                                     const int2* __restrict__ dslot,
                                                     const int* __restrict__ p_amask,
                                                     const int* __restrict__ p_nspad,
                                                     float* __restrict__ out) {
    const int amask = *p_amask;               // uniform scalar
    const int ngtot = __popc(amask);
    const int cn = ngtot < GCHUNK ? ngtot : GCHUNK;
    const v4f* x4 = (const v4f*)x;
    v4f* o4 = (v4f*)out;

    const int stride = gridDim.x * blockDim.x;     // 524288
    for (int i = blockIdx.x * blockDim.x + threadIdx.x; i < TOTALF4; i += stride) {
        v4f acc = x4[i];
        const int g = i % GROUPS;
        const int pixel = i / GROUPS;
        const bool act = (amask >> g) & 1;
        if (act) {
            int aidx = __popc(amask & ((1u << g) - 1));
            if (aidx < GCHUNK)
                acc += cvbuf[(size_t)pixel * cn + aidx];
            else {                            // uniform-rare scattered tail
                int rem = pixel % IMG;
                int h = rem / HW, w = rem - h * HW;
                const float* xb = x + (size_t)i * 4;
                int nsb = (*p_nspad) >> 3;
                for (int sb = 0; sb < nsb; ++sb) {
#pragma unroll
                    for (int si = 0; si < 8; ++si) {
                        int s = sb * 8 + si;
                        int2 dd = dslot[g * SLOTG + s];
                        int dh2 = dd.x, dw = dd.y;
                        bool valid = ((unsigned)(h + dh2 - 2) < (unsigned)HW) &
                                     ((unsigned)(w + dw) < (unsigned)HW);
                        float sc = valid ? 1.f : 0.f;
                        int off = valid ? ((dh2 - 2) * HW * CH + dw * CH) : 0;
                        v4f xv = *(const v4f*)(xb + off);
                        float4 wv = wslot[g * SLOTG + s];
                        acc.x += (wv.x * sc) * xv.x;
                        acc.y += (wv.y * sc) * xv.y;
                        acc.z += (wv.z * sc) * xv.z;
                        acc.w += (wv.w * sc) * xv.w;
                    }
                }
            }
        }
        o4[i] = acc;                          // plain store, dense 16B/lane
    }
}

// ---- Fallback (ws too small): monolithic, reads raw k — correctness only ----
__global__ __launch_bounds__(256) void fallback_kernel(const float* __restrict__ x,
                                                       const float* __restrict__ kraw,
                                                       float* __restrict__ out) {
    int t = blockIdx.x * 256 + threadIdx.x;
    if (t >= TOTALF4) return;
    int g = t % GROUPS;
    int pixel = t / GROUPS;
    int rem = pixel % IMG;
    int h = rem / HW;
    int w = rem - h * HW;
    int base = pixel * CH + g * 4;
    const float4 xc = *reinterpret_cast<const float4*>(x + base);
    float4 acc = make_float4(xc.x, xc.y, xc.z, xc.w);
#pragma unroll
    for (int dh = -2; dh <= 2; ++dh)
#pragma unroll
        for (int dw = -2; dw <= 2; ++dw) {
            const int tap = (dh + 2) * 5 + (dw + 2);
            const bool valid = ((unsigned)(h + dh) < (unsigned)HW) &
                               ((unsigned)(w + dw) < (unsigned)HW);
            const float vs = valid ? 1.0f : 0.0f;
            const int off = valid ? (dh * HW * CH + dw * CH) : 0;
            const float4 xv = *reinterpret_cast<const float4*>(x + base + off);
            acc.x += (kraw[(g * 4 + 0) * TAPS + tap] * vs) * xv.x;
            acc.y += (kraw[(g * 4 + 1) * TAPS + tap] * vs) * xv.y;
            acc.z += (kraw[(g * 4 + 2) * TAPS + tap] * vs) * xv.z;
            acc.w += (kraw[(g * 4 + 3) * TAPS + tap] * vs) * xv.w;
        }
    *reinterpret_cast<float4*>(out + base) = acc;
}

extern "C" void kernel_launch(void* const* d_in, const int* in_sizes, int n_in,
                              void* d_out, int out_size, void* d_ws, size_t ws_size,
                              hipStream_t stream) {
    const float* x = (const float*)d_in[0];
    const float* k = (const float*)d_in[1];
    float* out = (float*)d_out;

    const size_t sz_wslot = (size_t)GROUPS * SLOTG * sizeof(float4);   // 12288
    const size_t sz_dslot = (size_t)GROUPS * SLOTG * sizeof(int2);     // 6144
    const size_t sz_flag = GROUPS * sizeof(int);
    const size_t sz_gact = GROUPS * sizeof(int);
    const size_t sz_scalars = 3 * sizeof(int);
    size_t tab_bytes = sz_wslot + sz_dslot + sz_flag + sz_gact + sz_scalars;
    tab_bytes = (tab_bytes + 15) & ~(size_t)15;                        // align cvbuf
    const size_t sz_cvbuf = (size_t)NPIX * GCHUNK * sizeof(v4f);       // 24.8 MB

    if (ws_size >= tab_bytes + sz_cvbuf) {
        char* p = (char*)d_ws;
        float4* wslot = (float4*)p;  p += sz_wslot;
        int2* dslot = (int2*)p;      p += sz_dslot;
        int* tapflag = (int*)p;      p += sz_flag;
        int* gact = (int*)p;         p += sz_gact;
        int* nga = (int*)p;          p += sizeof(int);
        int* nspad = (int*)p;        p += sizeof(int);
        int* amask = (int*)p;
        v4f* cvbuf = (v4f*)((char*)d_ws + tab_bytes);

        repack_kernel<<<1, 64, 0, stream>>>(k, wslot, dslot, tapflag, gact,
                                            nga, nspad, amask);
        conv_kernel<<<NWG1, 256, 0, stream>>>(x, wslot, dslot, gact, nga, nspad,
                                              cvbuf);
        stream_kernel<<<STREAM_BLOCKS, 256, 0, stream>>>(x, cvbuf, wslot, dslot,
                                                         amask, nspad, out);
    } else {
        fallback_kernel<<<(TOTALF4 + 255) / 256, 256, 0, stream>>>(x, k, out);
    }
}

// Round 18
// 82.918 us; speedup vs baseline: 1.4474x; 1.4474x over previous
//
#include <hip/hip_runtime.h>

// x: (128, 55, 55, 96) NHWC fp32; kernel: (96, 5, 5) fp32 depthwise; out = x + dwconv(x,k)
#define NB 128
#define HW 55
#define IMG (HW * HW)            // 3025
#define CH 96
#define GROUPS 24                // float4 channel-groups
#define TAPS 25
#define NPIX (NB * IMG)
#define RSTRIP 5                 // output rows per block (55 = 5*11, exact)
#define NSTRIP (HW / RSTRIP)     // 11
#define NWG (NB * NSTRIP)        // 1408 blocks
#define SROWS (RSTRIP + 4)       // 9 staged rows (halo +-2)
#define GCHUNK 4                 // active groups staged per pass
#define SLOTG 32                 // per-group slot capacity in the global table
#define NXCD 8
#define BITEMS (RSTRIP * HW * GROUPS)  // 6600 f4 items per block
#define QTR (BITEMS / 4)         // 1650
#define SPIX (RSTRIP * HW)       // 275 strip pixels per block
#define STAGEN (SROWS * HW)      // 495 staged pixels

typedef float v4f __attribute__((ext_vector_type(4)));

// ---- workspace ----
// float4 wslot[24][SLOTG]; int2 dslot[24][SLOTG] ({dh+2, dw}); int tapflag[24];
// int gact[24] (ascending); int nga, nspad, amask

__global__ void repack_kernel(const float* __restrict__ k,
                              float4* __restrict__ wslot,
                              int2* __restrict__ dslot,
                              int* __restrict__ tapflag,
                              int* __restrict__ gact,
                              int* __restrict__ nga,
                              int* __restrict__ nspad,
                              int* __restrict__ amask) {
    __shared__ int s_ns[GROUPS];
    int g = threadIdx.x;
    if (g < GROUPS) {
        int ns = 0;
        for (int tap = 0; tap < TAPS; ++tap) {
            float w0 = k[(4 * g + 0) * TAPS + tap];
            float w1 = k[(4 * g + 1) * TAPS + tap];
            float w2 = k[(4 * g + 2) * TAPS + tap];
            float w3 = k[(4 * g + 3) * TAPS + tap];
            if (w0 != 0.f || w1 != 0.f || w2 != 0.f || w3 != 0.f) {
                int dh = tap / 5 - 2, dw = tap % 5 - 2;
                wslot[g * SLOTG + ns] = make_float4(w0, w1, w2, w3);
                dslot[g * SLOTG + ns] = make_int2(dh + 2, dw);
                ++ns;
            }
        }
        for (int s = ns; s < SLOTG; ++s) {           // pads: weight 0 -> contribute 0
            wslot[g * SLOTG + s] = make_float4(0.f, 0.f, 0.f, 0.f);
            dslot[g * SLOTG + s] = make_int2(2, 0);  // center, always valid
        }
        tapflag[g] = (ns > 0) ? 1 : 0;
        s_ns[g] = ns;
    }
    __syncthreads();
    if (threadIdx.x == 0) {
        int na = 0, m = 0, msk = 0;
        for (int gg = 0; gg < GROUPS; ++gg)          // ascending: popc-prefix == index
            if (s_ns[gg] > 0) {
                gact[na++] = gg;
                msk |= (1 << gg);
                m = m > s_ns[gg] ? m : s_ns[gg];
            }
        *nga = na;
        *nspad = (m + 7) & ~7;
        *amask = msk;
    }
}

// ---- fused tiled kernel: stage -> lane-dense conv -> 4-way-MLP dense stream ----
__global__ __launch_bounds__(256) void tiled_kernel(const float* __restrict__ x,
                                                    const float4* __restrict__ wslot,
                                                    const int2* __restrict__ dslot,
                                                    const int* __restrict__ gact,
                                                    const int* __restrict__ p_nga,
                                                    const int* __restrict__ p_nspad,
                                                    const int* __restrict__ p_amask,
                                                    float* __restrict__ out) {
    __shared__ v4f s_x[GCHUNK * STAGEN];      // planar halo tile     31680 B
    __shared__ v4f s_cv[GCHUNK * SPIX];       // conv deltas          17600 B
    __shared__ float4 s_w[GCHUNK * 8];        // first 8-slot batch     512 B
    __shared__ int s_d[GCHUNK * 8];           // packed (dh+2)<<8|(dw+2) 128 B

    // Bijective chunked XCD swizzle (1408 % 8 == 0): contiguous strips per XCD.
    const int q = NWG / NXCD, r = NWG % NXCD;
    int xcd = blockIdx.x & (NXCD - 1);
    int bidx = blockIdx.x >> 3;
    int swz = (xcd < r ? xcd * (q + 1) : r * (q + 1) + (xcd - r) * q) + bidx;

    const int n = swz / NSTRIP;
    const int strip = swz % NSTRIP;
    const int h0 = strip * RSTRIP;
    const int tid = threadIdx.x;
    const int nga = *p_nga;
    const int amask = *p_amask;               // uniform scalar
    const int nsb = (*p_nspad) >> 3;
    const int base_f4 = (n * IMG + h0 * HW) * GROUPS;
    const v4f* x4 = (const v4f*)x;
    v4f* o4 = (v4f*)out;

    int nchunk = (nga + GCHUNK - 1) / GCHUNK;
    if (nchunk < 1) nchunk = 1;               // nga==0 -> one pure-copy pass
    const bool single = (nchunk == 1);

    for (int c = 0; c < nchunk; ++c) {
        const int c0 = c * GCHUNK;
        int cn = nga - c0;
        if (cn > GCHUNK) cn = GCHUNK;
        if (cn < 0) cn = 0;

        if (tid < cn * 8) {                    // stage first slot batch
            int ci = tid >> 3, s = tid & 7;
            int gg = gact[c0 + ci];
            s_w[tid] = wslot[gg * SLOTG + s];
            int2 dd = dslot[gg * SLOTG + s];
            s_d[tid] = (dd.x << 8) | (dd.y + 2);
        }
        // stage x halo tile, 4-way MLP unrolled (independent loads issue together)
        const int stcnt = STAGEN * cn;
        const int wcn = HW * cn;
        const int sq = (stcnt + 3) >> 2;
        for (int jj = tid; jj < sq; jj += 256) {
            int idx[4];
            v4f val[4];
#pragma unroll
            for (int kq = 0; kq < 4; ++kq) {
                int i = jj + kq * sq;
                idx[kq] = -1;
                if (i < stcnt) {
                    int srow = i / wcn;
                    int rem2 = i - srow * wcn;
                    int pix = rem2 / cn;
                    int ci = rem2 - pix * cn;
                    int h = h0 - 2 + srow;
                    v4f v = {0.f, 0.f, 0.f, 0.f};
                    if ((unsigned)h < (unsigned)HW)
                        v = x4[(n * IMG + h * HW + pix) * GROUPS + gact[c0 + ci]];
                    idx[kq] = ci * STAGEN + srow * HW + pix;
                    val[kq] = v;
                }
            }
#pragma unroll
            for (int kq = 0; kq < 4; ++kq)
                if (idx[kq] >= 0) s_x[idx[kq]] = val[kq];
        }
        __syncthreads();

        // ---- phase A: lane-dense conv over (chunk-group, strip-pixel) items ----
        const int acnt = cn * SPIX;
        for (int j = tid; j < acnt; j += 256) {
            int ci = j / SPIX;
            int pixrel = j - ci * SPIX;
            int rr = pixrel / HW;
            int pix = pixrel - rr * HW;
            const v4f* sxg = s_x + ci * STAGEN;
            v4f acc = {0.f, 0.f, 0.f, 0.f};
#pragma unroll
            for (int si = 0; si < 8; ++si) {
                int d = s_d[ci * 8 + si];
                int srow = rr + (d >> 8);
                int pix2 = pix + (d & 255) - 2;
                bool valid = (unsigned)pix2 < (unsigned)HW;
                float sc = valid ? 1.f : 0.f;
                int p2 = valid ? pix2 : 0;
                v4f xv = sxg[srow * HW + p2];
                float4 wv = s_w[ci * 8 + si];
                acc.x += (wv.x * sc) * xv.x;
                acc.y += (wv.y * sc) * xv.y;
                acc.z += (wv.z * sc) * xv.z;
                acc.w += (wv.w * sc) * xv.w;
            }
            for (int sb = 1; sb < nsb; ++sb) {  // rare tail (generality; none here)
                int gg = gact[c0 + ci];
#pragma unroll
                for (int si = 0; si < 8; ++si) {
                    int s = sb * 8 + si;
                    int2 dd = dslot[gg * SLOTG + s];
                    int srow = rr + dd.x;
                    int pix2 = pix + dd.y;
                    bool valid = (unsigned)pix2 < (unsigned)HW;
                    float sc = valid ? 1.f : 0.f;
                    int p2 = valid ? pix2 : 0;
                    v4f xv = sxg[srow * HW + p2];
                    float4 wv = wslot[gg * SLOTG + s];
                    acc.x += (wv.x * sc) * xv.x;
                    acc.y += (wv.y * sc) * xv.y;
                    acc.z += (wv.z * sc) * xv.z;
                    acc.w += (wv.w * sc) * xv.w;
                }
            }
            s_cv[ci * SPIX + pixrel] = acc;
        }
        __syncthreads();

        // ---- phase B: dense stream, 4 independent quarters (4 loads in flight) ----
        for (int jj = tid; jj < QTR; jj += 256) {
            const int i0 = jj, i1 = jj + QTR, i2 = jj + 2 * QTR, i3 = jj + 3 * QTR;
            // 4 independent coalesced loads issued before any use
            v4f a0 = x4[base_f4 + i0];
            v4f a1 = x4[base_f4 + i1];
            v4f a2 = x4[base_f4 + i2];
            v4f a3 = x4[base_f4 + i3];
#pragma unroll
            for (int kq = 0; kq < 4; ++kq) {
                const int i = jj + kq * QTR;
                v4f acc = kq == 0 ? a0 : kq == 1 ? a1 : kq == 2 ? a2 : a3;
                int pr = i / GROUPS;
                int gout = i - pr * GROUPS;
                bool act = (amask >> gout) & 1;
                int aidx = __popc(amask & ((1u << gout) - 1));
                int local = aidx - c0;
                bool inchunk = act & (local >= 0) & (local < cn);
                if (inchunk) acc += s_cv[local * SPIX + pr];
                if (single || inchunk || (c == 0 && !act))
                    __builtin_nontemporal_store(acc, &o4[base_f4 + i]);
            }
        }
        if (c + 1 < nchunk) __syncthreads();   // before s_x/s_cv reuse
    }
}

// ---- Fallback (ws too small): monolithic, reads raw k — correctness only ----
__global__ __launch_bounds__(256) void fallback_kernel(const float* __restrict__ x,
                                                       const float* __restrict__ kraw,
                                                       float* __restrict__ out) {
    int t = blockIdx.x * 256 + threadIdx.x;
    if (t >= NPIX * GROUPS) return;
    int g = t % GROUPS;
    int pixel = t / GROUPS;
    int rem = pixel % IMG;
    int h = rem / HW;
    int w = rem - h * HW;
    int base = pixel * CH + g * 4;
    const float4 xc = *reinterpret_cast<const float4*>(x + base);
    float4 acc = make_float4(xc.x, xc.y, xc.z, xc.w);
#pragma unroll
    for (int dh = -2; dh <= 2; ++dh)
#pragma unroll
        for (int dw = -2; dw <= 2; ++dw) {
            const int tap = (dh + 2) * 5 + (dw + 2);
            const bool valid = ((unsigned)(h + dh) < (unsigned)HW) &
                               ((unsigned)(w + dw) < (unsigned)HW);
            const float vs = valid ? 1.0f : 0.0f;
            const int off = valid ? (dh * HW * CH + dw * CH) : 0;
            const float4 xv = *reinterpret_cast<const float4*>(x + base + off);
            acc.x += (kraw[(g * 4 + 0) * TAPS + tap] * vs) * xv.x;
            acc.y += (kraw[(g * 4 + 1) * TAPS + tap] * vs) * xv.y;
            acc.z += (kraw[(g * 4 + 2) * TAPS + tap] * vs) * xv.z;
            acc.w += (kraw[(g * 4 + 3) * TAPS + tap] * vs) * xv.w;
        }
    *reinterpret_cast<float4*>(out + base) = acc;
}

extern "C" void kernel_launch(void* const* d_in, const int* in_sizes, int n_in,
                              void* d_out, int out_size, void* d_ws, size_t ws_size,
                              hipStream_t stream) {
    const float* x = (const float*)d_in[0];
    const float* k = (const float*)d_in[1];
    float* out = (float*)d_out;

    const size_t sz_wslot = (size_t)GROUPS * SLOTG * sizeof(float4);   // 12288
    const size_t sz_dslot = (size_t)GROUPS * SLOTG * sizeof(int2);     // 6144
    const size_t sz_flag = GROUPS * sizeof(int);
    const size_t sz_gact = GROUPS * sizeof(int);
    const size_t ws_need = sz_wslot + sz_dslot + sz_flag + sz_gact + 3 * sizeof(int);

    if (ws_size >= ws_need) {
        char* p = (char*)d_ws;
        float4* wslot = (float4*)p;  p += sz_wslot;
        int2* dslot = (int2*)p;      p += sz_dslot;
        int* tapflag = (int*)p;      p += sz_flag;
        int* gact = (int*)p;         p += sz_gact;
        int* nga = (int*)p;          p += sizeof(int);
        int* nspad = (int*)p;        p += sizeof(int);
        int* amask = (int*)p;

        repack_kernel<<<1, 64, 0, stream>>>(k, wslot, dslot, tapflag, gact,
                                            nga, nspad, amask);
        tiled_kernel<<<NWG, 256, 0, stream>>>(x, wslot, dslot, gact, nga, nspad,
                                              amask, out);
    } else {
        const int blocks = (NPIX * GROUPS) / 256;
        fallback_kernel<<<blocks, 256, 0, stream>>>(x, k, out);
    }
}